// Round 1
// baseline (832.074 us; speedup 1.0000x reference)
//
#include <hip/hip_runtime.h>

#define IN_CH 128
#define OUT_CH 64

// Detect whether edge_index arrived as int64 (high dwords all zero) or int32.
__global__ void k_detect_idx64(const int* __restrict__ ei, int* __restrict__ flag) {
    if (blockIdx.x == 0 && threadIdx.x == 0) {
        int is64 = 1;
#pragma unroll
        for (int i = 0; i < 16; ++i)
            if (ei[2 * i + 1] != 0) is64 = 0;
        *flag = is64;
    }
}

// out[n][c] = bias[c]  (d_out is poisoned 0xAA before every call)
__global__ void k_init_out(float* __restrict__ out, const float* __restrict__ bias, int total) {
    int i = blockIdx.x * 256 + threadIdx.x;
    if (i < total) out[i] = bias[i & (OUT_CH - 1)];
}

// h[n][o] = sum_k x[n][k] * W[o][k]
// One wave covers the 64 output channels of one node (lane = channel).
// W staged transposed in LDS with +1 pad: word = k*65+ch -> bank (k+ch)%32,
// 2 lanes/bank = free (m136). x[node*128+k] is wave-uniform -> broadcast load.
__global__ __launch_bounds__(256) void k_gemm(const float* __restrict__ x,
                                              const float* __restrict__ W,
                                              float* __restrict__ h, int nNodes) {
    __shared__ float wt[IN_CH][OUT_CH + 1];  // wt[k][o] = W[o][k]
    for (int i = threadIdx.x; i < IN_CH * OUT_CH; i += 256) {
        int o = i >> 7;        // W is [64][128] row-major: i = o*128 + k
        int k = i & 127;
        wt[k][o] = W[i];
    }
    __syncthreads();

    int tid = blockIdx.x * 256 + threadIdx.x;
    int node = tid >> 6;
    int ch = tid & 63;
    if (node >= nNodes) return;

    const float* xr = x + (size_t)node * IN_CH;
    float acc = 0.f;
#pragma unroll
    for (int k = 0; k < IN_CH; k += 4) {
        float4 xv = *(const float4*)(xr + k);
        acc += xv.x * wt[k + 0][ch];
        acc += xv.y * wt[k + 1][ch];
        acc += xv.z * wt[k + 2][ch];
        acc += xv.w * wt[k + 3][ch];
    }
    h[(size_t)node * OUT_CH + ch] = acc;
}

// 16 threads per edge; each handles 4 channels (float4 gather of the 256B
// h-row -> full cacheline utilization), then 4 hw fp32 atomics into out[dst].
__global__ __launch_bounds__(256) void k_scatter(const int* __restrict__ ei,
                                                 const float* __restrict__ h,
                                                 float* __restrict__ out,
                                                 int nEdges, int nNodes,
                                                 const int* __restrict__ flag64) {
    int t = blockIdx.x * 256 + threadIdx.x;
    int e = t >> 4;
    if (e >= nEdges) return;
    int c = (t & 15) << 2;

    int src, dst;
    if (*flag64) {
        const long long* e64 = (const long long*)ei;
        src = (int)e64[e];
        dst = (int)e64[nEdges + e];
    } else {
        src = ei[e];
        dst = ei[nEdges + e];
    }
    // Safety: never write OOB even if the dtype guess is wrong.
    if ((unsigned)src >= (unsigned)nNodes || (unsigned)dst >= (unsigned)nNodes) return;

    float4 v = *(const float4*)(h + (size_t)src * OUT_CH + c);
    float* o = out + (size_t)dst * OUT_CH + c;
    unsafeAtomicAdd(o + 0, v.x);
    unsafeAtomicAdd(o + 1, v.y);
    unsafeAtomicAdd(o + 2, v.z);
    unsafeAtomicAdd(o + 3, v.w);
}

extern "C" void kernel_launch(void* const* d_in, const int* in_sizes, int n_in,
                              void* d_out, int out_size, void* d_ws, size_t ws_size,
                              hipStream_t stream) {
    const float* x    = (const float*)d_in[0];
    const int*   ei   = (const int*)d_in[1];
    const float* W    = (const float*)d_in[2];
    const float* bias = (const float*)d_in[3];
    float* out = (float*)d_out;

    int nNodes = in_sizes[0] / IN_CH;   // 50000
    int nEdges = in_sizes[1] / 2;       // 800000 (element count of [2,E] array)

    float* h   = (float*)d_ws;                                        // nNodes*64 fp32 = 12.8 MB
    int* flag  = (int*)((char*)d_ws + (size_t)nNodes * OUT_CH * sizeof(float));

    k_detect_idx64<<<1, 64, 0, stream>>>(ei, flag);
    k_init_out<<<(out_size + 255) / 256, 256, 0, stream>>>(out, bias, out_size);
    k_gemm<<<(nNodes * OUT_CH + 255) / 256, 256, 0, stream>>>(x, W, h, nNodes);

    long long sthreads = (long long)nEdges * 16;
    k_scatter<<<(int)((sthreads + 255) / 256), 256, 0, stream>>>(ei, h, out, nEdges, nNodes, flag);
}

// Round 2
// 275.297 us; speedup vs baseline: 3.0225x; 3.0225x over previous
//
#include <hip/hip_runtime.h>

#define IN_CH 128
#define OUT_CH 64

// ---------------- index dtype detect ----------------
__global__ void k_detect_idx64(const int* __restrict__ ei, int* __restrict__ flag) {
    if (blockIdx.x == 0 && threadIdx.x == 0) {
        int is64 = 1;
#pragma unroll
        for (int i = 0; i < 16; ++i)
            if (ei[2 * i + 1] != 0) is64 = 0;
        *flag = is64;
    }
}

// ---------------- convert to int32 + dst histogram ----------------
__global__ __launch_bounds__(256) void k_convert(const int* __restrict__ ei,
                                                 int* __restrict__ src32,
                                                 int* __restrict__ dst32,
                                                 int* __restrict__ cnt,
                                                 int nEdges, int nNodes,
                                                 const int* __restrict__ flag64) {
    int e = blockIdx.x * 256 + threadIdx.x;
    if (e >= nEdges) return;
    int src, dst;
    if (*flag64) {
        const long long* e64 = (const long long*)ei;
        src = (int)e64[e];
        dst = (int)e64[nEdges + e];
    } else {
        src = ei[e];
        dst = ei[nEdges + e];
    }
    if ((unsigned)src >= (unsigned)nNodes) src = 0;   // safety clamp
    if ((unsigned)dst >= (unsigned)nNodes) dst = 0;
    src32[e] = src;
    dst32[e] = dst;
    atomicAdd(&cnt[dst], 1);
}

// ---------------- exclusive scan over cnt[nNodes] -> offs ----------------
__global__ __launch_bounds__(256) void k_scan1(const int* __restrict__ cnt,
                                               int* __restrict__ offs,
                                               int* __restrict__ bsum, int n) {
    __shared__ int s[256];
    int i = blockIdx.x * 256 + threadIdx.x;
    int v = (i < n) ? cnt[i] : 0;
    s[threadIdx.x] = v;
    __syncthreads();
    int incl = v;
#pragma unroll
    for (int d = 1; d < 256; d <<= 1) {
        int t = (threadIdx.x >= d) ? s[threadIdx.x - d] : 0;
        __syncthreads();
        incl += t;
        s[threadIdx.x] = incl;
        __syncthreads();
    }
    if (i < n) offs[i] = incl - v;               // exclusive within block
    if (threadIdx.x == 255) bsum[blockIdx.x] = incl;
}

__global__ void k_scan2(int* __restrict__ bsum, int nBlocks) {
    // single block of 256; sequential chunked exclusive scan with carry
    __shared__ int s[256];
    int carry = 0;
    for (int base = 0; base < nBlocks; base += 256) {
        int i = base + threadIdx.x;
        int v = (i < nBlocks) ? bsum[i] : 0;
        s[threadIdx.x] = v;
        __syncthreads();
        int incl = v;
#pragma unroll
        for (int d = 1; d < 256; d <<= 1) {
            int t = (threadIdx.x >= d) ? s[threadIdx.x - d] : 0;
            __syncthreads();
            incl += t;
            s[threadIdx.x] = incl;
            __syncthreads();
        }
        if (i < nBlocks) bsum[i] = carry + incl - v;
        int total = s[255];
        __syncthreads();
        carry += total;
    }
}

__global__ __launch_bounds__(256) void k_scan3(int* __restrict__ offs,
                                               const int* __restrict__ bsum,
                                               int* __restrict__ cursor,
                                               int n, int nEdges) {
    int i = blockIdx.x * 256 + threadIdx.x;
    if (i < n) {
        int o = offs[i] + bsum[blockIdx.x];
        offs[i] = o;
        cursor[i] = o;
    }
    if (i == 0) offs[n] = nEdges;
}

// ---------------- bin fill: sorted_src bucketed by dst ----------------
__global__ __launch_bounds__(256) void k_fill(const int* __restrict__ src32,
                                              const int* __restrict__ dst32,
                                              int* __restrict__ cursor,
                                              int* __restrict__ sorted_src,
                                              int nEdges) {
    int e = blockIdx.x * 256 + threadIdx.x;
    if (e >= nEdges) return;
    int d = dst32[e];
    int p = atomicAdd(&cursor[d], 1);
    sorted_src[p] = src32[e];
}

// ---------------- h = x @ W^T ----------------
__global__ __launch_bounds__(256) void k_gemm(const float* __restrict__ x,
                                              const float* __restrict__ W,
                                              float* __restrict__ h, int nNodes) {
    __shared__ float wt[IN_CH][OUT_CH + 1];  // wt[k][o] = W[o][k]
    for (int i = threadIdx.x; i < IN_CH * OUT_CH; i += 256) {
        int o = i >> 7;
        int k = i & 127;
        wt[k][o] = W[i];
    }
    __syncthreads();

    int tid = blockIdx.x * 256 + threadIdx.x;
    int node = tid >> 6;
    int ch = tid & 63;
    if (node >= nNodes) return;

    const float* xr = x + (size_t)node * IN_CH;
    float acc = 0.f;
#pragma unroll
    for (int k = 0; k < IN_CH; k += 4) {
        float4 xv = *(const float4*)(xr + k);
        acc += xv.x * wt[k + 0][ch];
        acc += xv.y * wt[k + 1][ch];
        acc += xv.z * wt[k + 2][ch];
        acc += xv.w * wt[k + 3][ch];
    }
    h[(size_t)node * OUT_CH + ch] = acc;
}

// ---------------- gather-reduce: one wave per node, lane = channel ----------------
__global__ __launch_bounds__(256) void k_gather(const int* __restrict__ offs,
                                                const int* __restrict__ sorted_src,
                                                const float* __restrict__ h,
                                                const float* __restrict__ bias,
                                                float* __restrict__ out, int nNodes) {
    int tid = blockIdx.x * 256 + threadIdx.x;
    int node = tid >> 6;
    int ch = tid & 63;
    if (node >= nNodes) return;

    int b = offs[node];
    int e = offs[node + 1];
    float acc = 0.f;
    int i = b;
    // unroll by 4 for MLP
    for (; i + 4 <= e; i += 4) {
        int s0 = sorted_src[i + 0];
        int s1 = sorted_src[i + 1];
        int s2 = sorted_src[i + 2];
        int s3 = sorted_src[i + 3];
        float v0 = h[(size_t)s0 * OUT_CH + ch];
        float v1 = h[(size_t)s1 * OUT_CH + ch];
        float v2 = h[(size_t)s2 * OUT_CH + ch];
        float v3 = h[(size_t)s3 * OUT_CH + ch];
        acc += v0 + v1 + v2 + v3;
    }
    for (; i < e; ++i) {
        int s = sorted_src[i];
        acc += h[(size_t)s * OUT_CH + ch];
    }
    out[(size_t)node * OUT_CH + ch] = acc + bias[ch];
}

extern "C" void kernel_launch(void* const* d_in, const int* in_sizes, int n_in,
                              void* d_out, int out_size, void* d_ws, size_t ws_size,
                              hipStream_t stream) {
    const float* x    = (const float*)d_in[0];
    const int*   ei   = (const int*)d_in[1];
    const float* W    = (const float*)d_in[2];
    const float* bias = (const float*)d_in[3];
    float* out = (float*)d_out;

    int nNodes = in_sizes[0] / IN_CH;   // 50000
    int nEdges = in_sizes[1] / 2;       // 800000

    // workspace layout (256B aligned)
    char* p = (char*)d_ws;
    auto alloc = [&](size_t bytes) {
        char* r = p;
        p += (bytes + 255) & ~(size_t)255;
        return r;
    };
    float* h        = (float*)alloc((size_t)nNodes * OUT_CH * sizeof(float)); // 12.8 MB
    int* src32      = (int*)alloc((size_t)nEdges * sizeof(int));              // 3.2 MB
    int* dst32      = (int*)alloc((size_t)nEdges * sizeof(int));              // 3.2 MB
    int* sorted_src = (int*)alloc((size_t)nEdges * sizeof(int));              // 3.2 MB
    int* offs       = (int*)alloc((size_t)(nNodes + 1) * sizeof(int));
    int* cursor     = (int*)alloc((size_t)nNodes * sizeof(int));
    int* cnt        = (int*)alloc((size_t)nNodes * sizeof(int));
    int* bsum       = (int*)alloc(4096 * sizeof(int));
    int* flag       = (int*)alloc(sizeof(int));

    int nScanBlocks = (nNodes + 255) / 256;

    hipMemsetAsync(cnt, 0, (size_t)nNodes * sizeof(int), stream);
    k_detect_idx64<<<1, 64, 0, stream>>>(ei, flag);
    k_convert<<<(nEdges + 255) / 256, 256, 0, stream>>>(ei, src32, dst32, cnt, nEdges, nNodes, flag);
    k_scan1<<<nScanBlocks, 256, 0, stream>>>(cnt, offs, bsum, nNodes);
    k_scan2<<<1, 256, 0, stream>>>(bsum, nScanBlocks);
    k_scan3<<<nScanBlocks, 256, 0, stream>>>(offs, bsum, cursor, nNodes, nEdges);
    k_fill<<<(nEdges + 255) / 256, 256, 0, stream>>>(src32, dst32, cursor, sorted_src, nEdges);
    k_gemm<<<(nNodes * OUT_CH + 255) / 256, 256, 0, stream>>>(x, W, h, nNodes);
    k_gather<<<(nNodes * OUT_CH + 255) / 256, 256, 0, stream>>>(offs, sorted_src, h, bias, out, nNodes);
}

// Round 4
// 190.646 us; speedup vs baseline: 4.3645x; 1.4440x over previous
//
#include <hip/hip_runtime.h>

#define IN_CH 128
#define OUT_CH 64
#define TN 64            // nodes per gemm block
#define XS_STRIDE 132    // padded x-tile stride  (bank (4n+k)%32 -> 2-way, free)
#define WS_STRIDE 129    // padded W staging stride (bank (o+k)%32 -> conflict-free transpose)

// ---------------- fused: zero cnt + detect int64 indices ----------------
__global__ __launch_bounds__(256) void k_init(const int* __restrict__ ei,
                                              int* __restrict__ cnt,
                                              int* __restrict__ flag, int nNodes) {
    int i = blockIdx.x * 256 + threadIdx.x;
    if (i < nNodes) cnt[i] = 0;
    if (blockIdx.x == 0 && threadIdx.x == 0) {
        int is64 = 1;
#pragma unroll
        for (int j = 0; j < 16; ++j)
            if (ei[2 * j + 1] != 0) is64 = 0;
        *flag = is64;
    }
}

// ---------------- convert + histogram + rank pack ----------------
// packed[e] = dst | (rank << 16)   (requires nNodes < 65536; here 50000)
__global__ __launch_bounds__(256) void k_convert(const int* __restrict__ ei,
                                                 int* __restrict__ src32,
                                                 unsigned* __restrict__ packed,
                                                 int* __restrict__ cnt,
                                                 int nEdges, int nNodes,
                                                 const int* __restrict__ flag64) {
    int e = blockIdx.x * 256 + threadIdx.x;
    if (e >= nEdges) return;
    int src, dst;
    if (*flag64) {
        const long long* e64 = (const long long*)ei;
        src = (int)e64[e];
        dst = (int)e64[nEdges + e];
    } else {
        src = ei[e];
        dst = ei[nEdges + e];
    }
    if ((unsigned)src >= (unsigned)nNodes) src = 0;
    if ((unsigned)dst >= (unsigned)nNodes) dst = 0;
    src32[e] = src;
    unsigned rank = (unsigned)atomicAdd(&cnt[dst], 1);
    packed[e] = (unsigned)dst | (rank << 16);
}

// ---------------- exclusive scan over cnt[nNodes] -> offs ----------------
__global__ __launch_bounds__(256) void k_scan1(const int* __restrict__ cnt,
                                               int* __restrict__ offs,
                                               int* __restrict__ bsum, int n) {
    __shared__ int s[256];
    int i = blockIdx.x * 256 + threadIdx.x;
    int v = (i < n) ? cnt[i] : 0;
    s[threadIdx.x] = v;
    __syncthreads();
    int incl = v;
#pragma unroll
    for (int d = 1; d < 256; d <<= 1) {
        int t = (threadIdx.x >= d) ? s[threadIdx.x - d] : 0;
        __syncthreads();
        incl += t;
        s[threadIdx.x] = incl;
        __syncthreads();
    }
    if (i < n) offs[i] = incl - v;
    if (threadIdx.x == 255) bsum[blockIdx.x] = incl;
}

__global__ void k_scan2(int* __restrict__ bsum, int nBlocks) {
    __shared__ int s[256];
    int carry = 0;
    for (int base = 0; base < nBlocks; base += 256) {
        int i = base + threadIdx.x;
        int v = (i < nBlocks) ? bsum[i] : 0;
        s[threadIdx.x] = v;
        __syncthreads();
        int incl = v;
#pragma unroll
        for (int d = 1; d < 256; d <<= 1) {
            int t = (threadIdx.x >= d) ? s[threadIdx.x - d] : 0;
            __syncthreads();
            incl += t;
            s[threadIdx.x] = incl;
            __syncthreads();
        }
        if (i < nBlocks) bsum[i] = carry + incl - v;
        int total = s[255];
        __syncthreads();
        carry += total;
    }
}

__global__ __launch_bounds__(256) void k_scan3(int* __restrict__ offs,
                                               const int* __restrict__ bsum,
                                               int n, int nEdges) {
    int i = blockIdx.x * 256 + threadIdx.x;
    if (i < n) offs[i] += bsum[blockIdx.x];
    if (i == 0) offs[n] = nEdges;
}

// ---------------- bin fill (no atomics: pos = offs[dst] + rank) ----------------
__global__ __launch_bounds__(256) void k_fill(const int* __restrict__ src32,
                                              const unsigned* __restrict__ packed,
                                              const int* __restrict__ offs,
                                              int* __restrict__ sorted_src,
                                              int nEdges) {
    int e = blockIdx.x * 256 + threadIdx.x;
    if (e >= nEdges) return;
    unsigned pk = packed[e];
    int d = (int)(pk & 0xFFFFu);
    int r = (int)(pk >> 16);
    int pos = offs[d] + r;
    if ((unsigned)pos < (unsigned)nEdges) sorted_src[pos] = src32[e];
}

// ---------------- h = x @ W^T : register-tiled ----------------
// Block: 256 threads -> 64 nodes x 64 ch. Thread (tx,ty): 4 nodes x 4 ch.
__device__ __forceinline__ void fma4(float4& acc, float s, const float4& wv) {
    acc.x += s * wv.x;
    acc.y += s * wv.y;
    acc.z += s * wv.z;
    acc.w += s * wv.w;
}

__global__ __launch_bounds__(256) void k_gemm(const float* __restrict__ x,
                                              const float* __restrict__ W,
                                              float* __restrict__ h, int nNodes) {
    __shared__ float smem[TN * XS_STRIDE + IN_CH * OUT_CH];  // 8448 + 8192 floats = 66.5 KB
    float* u  = smem;                   // ws (64 x str129) then reused as xs (64 x str132)
    float* wt = smem + TN * XS_STRIDE;  // wt[k][o]

    int tid = threadIdx.x;
    int nodeBase = blockIdx.x * TN;

    // 1) stage W coalesced into ws[o][k] (stride 129)
    {
        const float4* W4 = (const float4*)W;
        for (int i = tid; i < IN_CH * OUT_CH / 4; i += 256) {
            float4 v = W4[i];
            int o = i >> 5;            // 32 float4 per 128-float row
            int k = (i & 31) * 4;
            float* d = u + o * WS_STRIDE + k;
            d[0] = v.x; d[1] = v.y; d[2] = v.z; d[3] = v.w;
        }
    }
    __syncthreads();
    // 2) transpose ws -> wt[k][o] (read banks (o+k)%32, write banks o%32: both <=2-way)
    {
        int o = tid & 63;
        int k0 = (tid >> 6) * 32;
#pragma unroll 8
        for (int k = k0; k < k0 + 32; ++k)
            wt[k * OUT_CH + o] = u[o * WS_STRIDE + k];
    }
    __syncthreads();
    // 3) stage x tile into xs (stride 132), overwriting ws
    {
        int remRows = nNodes - nodeBase;
        if (remRows > TN) remRows = TN;
        const float4* X4 = (const float4*)(x + (size_t)nodeBase * IN_CH);
        for (int i = tid; i < TN * IN_CH / 4; i += 256) {
            int r = i >> 5;
            int k = (i & 31) * 4;
            float4 v = make_float4(0.f, 0.f, 0.f, 0.f);
            if (r < remRows) v = X4[i];
            *(float4*)(u + r * XS_STRIDE + k) = v;
        }
    }
    __syncthreads();

    int tx = tid & 15;   // channel group: c0 = tx*4
    int ty = tid >> 4;   // node group: n = ty*4 + i

    float4 acc[4];
#pragma unroll
    for (int i = 0; i < 4; ++i) acc[i] = make_float4(0.f, 0.f, 0.f, 0.f);

    const float* wcol = wt + tx * 4;
#pragma unroll 4
    for (int k = 0; k < IN_CH; k += 4) {
        float4 w0 = *(const float4*)(wcol + (k + 0) * OUT_CH);
        float4 w1 = *(const float4*)(wcol + (k + 1) * OUT_CH);
        float4 w2 = *(const float4*)(wcol + (k + 2) * OUT_CH);
        float4 w3 = *(const float4*)(wcol + (k + 3) * OUT_CH);
#pragma unroll
        for (int i = 0; i < 4; ++i) {
            float4 a = *(const float4*)(u + (ty * 4 + i) * XS_STRIDE + k);
            fma4(acc[i], a.x, w0);
            fma4(acc[i], a.y, w1);
            fma4(acc[i], a.z, w2);
            fma4(acc[i], a.w, w3);
        }
    }

#pragma unroll
    for (int i = 0; i < 4; ++i) {
        int n = nodeBase + ty * 4 + i;
        if (n < nNodes)
            *(float4*)(h + (size_t)n * OUT_CH + tx * 4) = acc[i];
    }
}

// ---------------- gather-reduce: one wave per node, lane = channel ----------------
__global__ __launch_bounds__(256) void k_gather(const int* __restrict__ offs,
                                                const int* __restrict__ sorted_src,
                                                const float* __restrict__ h,
                                                const float* __restrict__ bias,
                                                float* __restrict__ out, int nNodes) {
    int tid = blockIdx.x * 256 + threadIdx.x;
    int node = tid >> 6;
    int ch = tid & 63;
    if (node >= nNodes) return;

    int b = offs[node];
    int e = offs[node + 1];
    float acc = 0.f;
    int i = b;
    for (; i + 4 <= e; i += 4) {
        int s0 = sorted_src[i + 0];
        int s1 = sorted_src[i + 1];
        int s2 = sorted_src[i + 2];
        int s3 = sorted_src[i + 3];
        float v0 = h[(size_t)s0 * OUT_CH + ch];
        float v1 = h[(size_t)s1 * OUT_CH + ch];
        float v2 = h[(size_t)s2 * OUT_CH + ch];
        float v3 = h[(size_t)s3 * OUT_CH + ch];
        acc += v0 + v1 + v2 + v3;
    }
    for (; i < e; ++i)
        acc += h[(size_t)sorted_src[i] * OUT_CH + ch];
    out[(size_t)node * OUT_CH + ch] = acc + bias[ch];
}

extern "C" void kernel_launch(void* const* d_in, const int* in_sizes, int n_in,
                              void* d_out, int out_size, void* d_ws, size_t ws_size,
                              hipStream_t stream) {
    const float* x    = (const float*)d_in[0];
    const int*   ei   = (const int*)d_in[1];
    const float* W    = (const float*)d_in[2];
    const float* bias = (const float*)d_in[3];
    float* out = (float*)d_out;

    int nNodes = in_sizes[0] / IN_CH;   // 50000
    int nEdges = in_sizes[1] / 2;       // 800000

    char* p = (char*)d_ws;
    auto alloc = [&](size_t bytes) {
        char* r = p;
        p += (bytes + 255) & ~(size_t)255;
        return r;
    };
    float*    h          = (float*)alloc((size_t)nNodes * OUT_CH * sizeof(float));
    int*      src32      = (int*)alloc((size_t)nEdges * sizeof(int));
    unsigned* packed     = (unsigned*)alloc((size_t)nEdges * sizeof(unsigned));
    int*      sorted_src = (int*)alloc((size_t)nEdges * sizeof(int));
    int*      offs       = (int*)alloc((size_t)(nNodes + 1) * sizeof(int));
    int*      cnt        = (int*)alloc((size_t)nNodes * sizeof(int));
    int*      bsum       = (int*)alloc(4096 * sizeof(int));
    int*      flag       = (int*)alloc(sizeof(int));

    int nScanBlocks = (nNodes + 255) / 256;

    k_init<<<nScanBlocks, 256, 0, stream>>>(ei, cnt, flag, nNodes);
    k_convert<<<(nEdges + 255) / 256, 256, 0, stream>>>(ei, src32, packed, cnt, nEdges, nNodes, flag);
    k_scan1<<<nScanBlocks, 256, 0, stream>>>(cnt, offs, bsum, nNodes);
    k_scan2<<<1, 256, 0, stream>>>(bsum, nScanBlocks);
    k_scan3<<<nScanBlocks, 256, 0, stream>>>(offs, bsum, nNodes, nEdges);
    k_fill<<<(nEdges + 255) / 256, 256, 0, stream>>>(src32, packed, offs, sorted_src, nEdges);
    k_gemm<<<(nNodes + TN - 1) / TN, 256, 0, stream>>>(x, W, h, nNodes);
    k_gather<<<(nNodes * OUT_CH + 255) / 256, 256, 0, stream>>>(offs, sorted_src, h, bias, out, nNodes);
}

// Round 5
// 184.013 us; speedup vs baseline: 4.5218x; 1.0360x over previous
//
#include <hip/hip_runtime.h>

#define IN_CH 128
#define OUT_CH 64
#define TN 64            // nodes per gemm block
#define XS_STRIDE 132    // padded x-tile stride  (bank (4n+k)%32 -> 2-way, free)
#define WS_STRIDE 129    // padded W staging stride (bank (o+k)%32 -> conflict-free transpose)

// fp32 -> bf16 (RNE) and back, done manually to avoid header friction
__device__ __forceinline__ unsigned f2bf(float f) {
    unsigned u = __float_as_uint(f);
    return (u + 0x7FFFu + ((u >> 16) & 1u)) >> 16;
}

// ---------------- fused: zero cnt + detect int64 indices ----------------
__global__ __launch_bounds__(256) void k_init(const int* __restrict__ ei,
                                              int* __restrict__ cnt,
                                              int* __restrict__ flag, int nNodes) {
    int i = blockIdx.x * 256 + threadIdx.x;
    if (i < nNodes) cnt[i] = 0;
    if (blockIdx.x == 0 && threadIdx.x == 0) {
        int is64 = 1;
#pragma unroll
        for (int j = 0; j < 16; ++j)
            if (ei[2 * j + 1] != 0) is64 = 0;
        *flag = is64;
    }
}

// ---------------- convert + histogram + rank pack ----------------
// packed[e] = dst | (rank << 16)   (nNodes = 50000 < 65536)
__global__ __launch_bounds__(256) void k_convert(const int* __restrict__ ei,
                                                 int* __restrict__ src32,
                                                 unsigned* __restrict__ packed,
                                                 int* __restrict__ cnt,
                                                 int nEdges, int nNodes,
                                                 const int* __restrict__ flag64) {
    int e = blockIdx.x * 256 + threadIdx.x;
    if (e >= nEdges) return;
    int src, dst;
    if (*flag64) {
        const long long* e64 = (const long long*)ei;
        src = (int)e64[e];
        dst = (int)e64[nEdges + e];
    } else {
        src = ei[e];
        dst = ei[nEdges + e];
    }
    if ((unsigned)src >= (unsigned)nNodes) src = 0;
    if ((unsigned)dst >= (unsigned)nNodes) dst = 0;
    src32[e] = src;
    unsigned rank = (unsigned)atomicAdd(&cnt[dst], 1);
    packed[e] = (unsigned)dst | (rank << 16);
}

// ---------------- per-block exclusive scan over cnt -> offs (block-local) ----------------
__global__ __launch_bounds__(256) void k_scan1(const int* __restrict__ cnt,
                                               int* __restrict__ offs,
                                               int* __restrict__ bsum, int n) {
    __shared__ int s[256];
    int i = blockIdx.x * 256 + threadIdx.x;
    int v = (i < n) ? cnt[i] : 0;
    s[threadIdx.x] = v;
    __syncthreads();
    int incl = v;
#pragma unroll
    for (int d = 1; d < 256; d <<= 1) {
        int t = (threadIdx.x >= d) ? s[threadIdx.x - d] : 0;
        __syncthreads();
        incl += t;
        s[threadIdx.x] = incl;
        __syncthreads();
    }
    if (i < n) offs[i] = incl - v;
    if (threadIdx.x == 255) bsum[blockIdx.x] = incl;
}

// scan of block sums (nBlocks <= 256 here after one chunk; loop keeps it general)
__global__ void k_scan2(int* __restrict__ bsum, int nBlocks) {
    __shared__ int s[256];
    int carry = 0;
    for (int base = 0; base < nBlocks; base += 256) {
        int i = base + threadIdx.x;
        int v = (i < nBlocks) ? bsum[i] : 0;
        s[threadIdx.x] = v;
        __syncthreads();
        int incl = v;
#pragma unroll
        for (int d = 1; d < 256; d <<= 1) {
            int t = (threadIdx.x >= d) ? s[threadIdx.x - d] : 0;
            __syncthreads();
            incl += t;
            s[threadIdx.x] = incl;
            __syncthreads();
        }
        if (i < nBlocks) bsum[i] = carry + incl - v;
        int total = s[255];
        __syncthreads();
        carry += total;
    }
}

// ---------------- bin fill: pos = offs[d] + bsum[d>>8] + rank, no atomics ----------------
__global__ __launch_bounds__(256) void k_fill(const int* __restrict__ src32,
                                              const unsigned* __restrict__ packed,
                                              const int* __restrict__ offs,
                                              const int* __restrict__ bsum,
                                              int* __restrict__ sorted_src,
                                              int nEdges) {
    int e = blockIdx.x * 256 + threadIdx.x;
    if (e >= nEdges) return;
    unsigned pk = packed[e];
    int d = (int)(pk & 0xFFFFu);
    int r = (int)(pk >> 16);
    int pos = offs[d] + bsum[d >> 8] + r;
    if ((unsigned)pos < (unsigned)nEdges) sorted_src[pos] = src32[e];
}

// ---------------- h = x @ W^T, h stored as bf16 (packed pairs in uint) ----------------
__device__ __forceinline__ void fma4(float4& acc, float s, const float4& wv) {
    acc.x += s * wv.x;
    acc.y += s * wv.y;
    acc.z += s * wv.z;
    acc.w += s * wv.w;
}

__global__ __launch_bounds__(256) void k_gemm(const float* __restrict__ x,
                                              const float* __restrict__ W,
                                              unsigned* __restrict__ h16,  // [node][32] bf16x2
                                              int nNodes) {
    __shared__ float smem[TN * XS_STRIDE + IN_CH * OUT_CH];
    float* u  = smem;                   // W staging (str 129) then x tile (str 132)
    float* wt = smem + TN * XS_STRIDE;  // wt[k][o]

    int tid = threadIdx.x;
    int nodeBase = blockIdx.x * TN;

    {
        const float4* W4 = (const float4*)W;
        for (int i = tid; i < IN_CH * OUT_CH / 4; i += 256) {
            float4 v = W4[i];
            int o = i >> 5;
            int k = (i & 31) * 4;
            float* d = u + o * WS_STRIDE + k;
            d[0] = v.x; d[1] = v.y; d[2] = v.z; d[3] = v.w;
        }
    }
    __syncthreads();
    {
        int o = tid & 63;
        int k0 = (tid >> 6) * 32;
#pragma unroll 8
        for (int k = k0; k < k0 + 32; ++k)
            wt[k * OUT_CH + o] = u[o * WS_STRIDE + k];
    }
    __syncthreads();
    {
        int remRows = nNodes - nodeBase;
        if (remRows > TN) remRows = TN;
        const float4* X4 = (const float4*)(x + (size_t)nodeBase * IN_CH);
        for (int i = tid; i < TN * IN_CH / 4; i += 256) {
            int r = i >> 5;
            int k = (i & 31) * 4;
            float4 v = make_float4(0.f, 0.f, 0.f, 0.f);
            if (r < remRows) v = X4[i];
            *(float4*)(u + r * XS_STRIDE + k) = v;
        }
    }
    __syncthreads();

    int tx = tid & 15;   // channel group: c0 = tx*4
    int ty = tid >> 4;   // node group

    float4 acc[4];
#pragma unroll
    for (int i = 0; i < 4; ++i) acc[i] = make_float4(0.f, 0.f, 0.f, 0.f);

    const float* wcol = wt + tx * 4;
#pragma unroll 4
    for (int k = 0; k < IN_CH; k += 4) {
        float4 w0 = *(const float4*)(wcol + (k + 0) * OUT_CH);
        float4 w1 = *(const float4*)(wcol + (k + 1) * OUT_CH);
        float4 w2 = *(const float4*)(wcol + (k + 2) * OUT_CH);
        float4 w3 = *(const float4*)(wcol + (k + 3) * OUT_CH);
#pragma unroll
        for (int i = 0; i < 4; ++i) {
            float4 a = *(const float4*)(u + (ty * 4 + i) * XS_STRIDE + k);
            fma4(acc[i], a.x, w0);
            fma4(acc[i], a.y, w1);
            fma4(acc[i], a.z, w2);
            fma4(acc[i], a.w, w3);
        }
    }

#pragma unroll
    for (int i = 0; i < 4; ++i) {
        int n = nodeBase + ty * 4 + i;
        if (n < nNodes) {
            uint2 pk;
            pk.x = f2bf(acc[i].x) | (f2bf(acc[i].y) << 16);
            pk.y = f2bf(acc[i].z) | (f2bf(acc[i].w) << 16);
            *(uint2*)(h16 + (size_t)n * 32 + tx * 2) = pk;
        }
    }
}

// ---------------- gather-reduce: one wave per node, 2 edges per iteration ----------------
// lane = (half<<5)|cp : half selects even/odd edge, cp = channel pair (bf16x2).
__global__ __launch_bounds__(256) void k_gather(const int* __restrict__ offs,
                                                const int* __restrict__ bsum,
                                                const int* __restrict__ sorted_src,
                                                const unsigned* __restrict__ h16,
                                                const float* __restrict__ bias,
                                                float* __restrict__ out,
                                                int nNodes, int nEdges) {
    int tid = blockIdx.x * 256 + threadIdx.x;
    int node = tid >> 6;
    if (node >= nNodes) return;
    int lane = tid & 63;
    int half = lane >> 5;
    int cp   = lane & 31;

    int b = offs[node] + bsum[node >> 8];
    int e = (node == nNodes - 1) ? nEdges : (offs[node + 1] + bsum[(node + 1) >> 8]);

    float2 acc = {0.f, 0.f};
    int i = b + half;
    for (; i + 2 < e; i += 4) {  // this half handles edges i and i+2
        int s0 = sorted_src[i];
        int s1 = sorted_src[i + 2];
        unsigned v0 = h16[(size_t)s0 * 32 + cp];
        unsigned v1 = h16[(size_t)s1 * 32 + cp];
        acc.x += __uint_as_float(v0 << 16);
        acc.y += __uint_as_float(v0 & 0xFFFF0000u);
        acc.x += __uint_as_float(v1 << 16);
        acc.y += __uint_as_float(v1 & 0xFFFF0000u);
    }
    if (i < e) {
        int s = sorted_src[i];
        unsigned v = h16[(size_t)s * 32 + cp];
        acc.x += __uint_as_float(v << 16);
        acc.y += __uint_as_float(v & 0xFFFF0000u);
    }

    // combine halves: lane l (<32) += lane l+32
    acc.x += __shfl_down(acc.x, 32, 64);
    acc.y += __shfl_down(acc.y, 32, 64);
    if (half == 0) {
        float2 bv = *(const float2*)(bias + cp * 2);
        float2 o;
        o.x = acc.x + bv.x;
        o.y = acc.y + bv.y;
        *(float2*)(out + (size_t)node * OUT_CH + cp * 2) = o;
    }
}

extern "C" void kernel_launch(void* const* d_in, const int* in_sizes, int n_in,
                              void* d_out, int out_size, void* d_ws, size_t ws_size,
                              hipStream_t stream) {
    const float* x    = (const float*)d_in[0];
    const int*   ei   = (const int*)d_in[1];
    const float* W    = (const float*)d_in[2];
    const float* bias = (const float*)d_in[3];
    float* out = (float*)d_out;

    int nNodes = in_sizes[0] / IN_CH;   // 50000
    int nEdges = in_sizes[1] / 2;       // 800000

    char* p = (char*)d_ws;
    auto alloc = [&](size_t bytes) {
        char* r = p;
        p += (bytes + 255) & ~(size_t)255;
        return r;
    };
    unsigned* h16        = (unsigned*)alloc((size_t)nNodes * 32 * sizeof(unsigned)); // 6.4 MB
    int*      src32      = (int*)alloc((size_t)nEdges * sizeof(int));
    unsigned* packed     = (unsigned*)alloc((size_t)nEdges * sizeof(unsigned));
    int*      sorted_src = (int*)alloc((size_t)nEdges * sizeof(int));
    int*      offs       = (int*)alloc((size_t)nNodes * sizeof(int));
    int*      cnt        = (int*)alloc((size_t)nNodes * sizeof(int));
    int*      bsum       = (int*)alloc(4096 * sizeof(int));
    int*      flag       = (int*)alloc(sizeof(int));

    int nScanBlocks = (nNodes + 255) / 256;

    k_init<<<nScanBlocks, 256, 0, stream>>>(ei, cnt, flag, nNodes);
    k_convert<<<(nEdges + 255) / 256, 256, 0, stream>>>(ei, src32, packed, cnt, nEdges, nNodes, flag);
    k_gemm<<<(nNodes + TN - 1) / TN, 256, 0, stream>>>(x, W, h16, nNodes);
    k_scan1<<<nScanBlocks, 256, 0, stream>>>(cnt, offs, bsum, nNodes);
    k_scan2<<<1, 256, 0, stream>>>(bsum, nScanBlocks);
    k_fill<<<(nEdges + 255) / 256, 256, 0, stream>>>(src32, packed, offs, bsum, sorted_src, nEdges);
    k_gather<<<(nNodes * OUT_CH + 255) / 256, 256, 0, stream>>>(offs, bsum, sorted_src, h16, bias, out, nNodes, nEdges);
}